// Round 3
// baseline (285.796 us; speedup 1.0000x reference)
//
#include <hip/hip_runtime.h>

#define NN 6000
#define EE 144000

typedef __attribute__((ext_vector_type(8))) short bf16x8;
typedef __attribute__((ext_vector_type(4))) float f32x4;

__device__ __forceinline__ unsigned short f2bf(float f) {
  unsigned int u = __float_as_uint(f);
  u += 0x7FFF + ((u >> 16) & 1);
  return (unsigned short)(u >> 16);
}
__device__ __forceinline__ float bf2f(unsigned short u) {
  return __uint_as_float(((unsigned int)u) << 16);
}
__device__ __forceinline__ float lexp(float v) {
  v = v > 0.f ? v : 0.2f * v;   // leaky_relu(0.2) then exp
  return __expf(v);
}

// ---- workspace zeroing (replaces hipMemsetAsync graph node) --------------
__global__ void k_zero(uint4* __restrict__ p, int n16) {
  int i = blockIdx.x * 256 + threadIdx.x;
  if (i < n16) p[i] = uint4{0, 0, 0, 0};
}

// ---- prep: weight repacks + x->bf16 (both branches, one launch) ----------
__global__ void k_prep(const float* __restrict__ gW0, const float* __restrict__ gW1,
                       const float* __restrict__ g1W0, const float* __restrict__ g1W1,
                       const float* __restrict__ g2W0, const float* __restrict__ g2W1,
                       const float* __restrict__ cW0, const float* __restrict__ cW1,
                       const float* __restrict__ x0, const float* __restrict__ x1,
                       unsigned short* __restrict__ BcatT,
                       unsigned short* __restrict__ cWb,
                       unsigned short* __restrict__ xb) {
  int idx = blockIdx.x * 256 + threadIdx.x;
  if (idx < 327680) {
    int b = idx / 163840;
    int r = idx % 163840;
    int L = r / 81920;
    int r2 = r % 81920;
    int j = r2 / 128, k = r2 % 128;
    const float* gW = b ? gW1 : gW0;
    const float* WL = L ? (b ? g2W1 : g2W0) : (b ? g1W1 : g1W0);
    float v = (j < 512) ? gW[k * 512 + j] : WL[k * 128 + (j - 512)];
    BcatT[idx] = f2bf(v);
  } else if (idx < 393216) {
    int i2 = idx - 327680;
    int b = i2 >> 15;
    int ok = i2 & 32767;
    cWb[i2] = f2bf((b ? cW1 : cW0)[ok]);
  } else {
    int i3 = idx - 393216;   // < 1,536,000
    int b = i3 >= 768000;
    int local = i3 - b * 768000;
    xb[i3] = f2bf((b ? x1 : x0)[local]);
  }
}

// ---- degrees / counts / mean(ew) -----------------------------------------
__global__ void k_deg(const int* __restrict__ ei0, const int* __restrict__ ei1,
                      const float* __restrict__ ew0, const float* __restrict__ ew1,
                      float* __restrict__ deg, int* __restrict__ cnt,
                      float* __restrict__ easum) {
  int b = blockIdx.y;
  int e = blockIdx.x * 256 + threadIdx.x;
  const int* ei = b ? ei1 : ei0;
  const float* ew = b ? ew1 : ew0;
  float w = 0.f;
  if (e < EE) {
    int c = ei[EE + e];
    w = ew[e];
    atomicAdd(deg + b * NN + c, w);
    atomicAdd(cnt + b * NN + c, 1);
  }
  __shared__ float red[256];
  red[threadIdx.x] = w;
  __syncthreads();
  for (int off = 128; off > 0; off >>= 1) {
    if (threadIdx.x < off) red[threadIdx.x] += red[threadIdx.x + off];
    __syncthreads();
  }
  if (threadIdx.x == 0) atomicAdd(easum + b, red[0]);
}

// ---- dinv + per-head edge-weight dots wd ---------------------------------
__global__ void k_dinv(const float* __restrict__ deg, float* __restrict__ dinv,
                       const float* __restrict__ We0, const float* __restrict__ We1,
                       const float* __restrict__ ae0, const float* __restrict__ ae1,
                       float* __restrict__ wd) {
  int i = blockIdx.x * 256 + threadIdx.x;
  if (i < 2 * NN) dinv[i] = rsqrtf(deg[i] + 1.0f);   // +1 = self-loop weight
  if (blockIdx.x < 2) {
    int b = blockIdx.x;
    const float* We = b ? We1 : We0;
    const float* ae = b ? ae1 : ae0;
    int t = threadIdx.x;
    int h = t >> 6, lane = t & 63;
    int f = h * 128 + lane * 2;
    float p = We[f] * ae[f] + We[f + 1] * ae[f + 1];
    for (int off = 32; off > 0; off >>= 1) p += __shfl_down(p, off);
    if (lane == 0) wd[b * 4 + h] = p;
  }
}

// ---- exclusive-scan of per-node counts -> CSR row ptr (1 block/branch) ---
__global__ __launch_bounds__(1024) void k_scan(const int* __restrict__ cnt,
                                               int* __restrict__ rp) {
  int b = blockIdx.x;
  const int* c = cnt + b * NN;
  int* r = rp + b * (NN + 1);
  __shared__ int wsum[16];
  __shared__ int carry;
  int t = threadIdx.x, lane = t & 63, wid = t >> 6;
  if (t == 0) { carry = 0; r[0] = 0; }
  __syncthreads();
  for (int base = 0; base < NN; base += 1024) {
    int v = (base + t < NN) ? c[base + t] : 0;
#pragma unroll
    for (int off = 1; off < 64; off <<= 1) {
      int u = __shfl_up(v, off);
      if (lane >= off) v += u;
    }
    if (lane == 63) wsum[wid] = v;
    __syncthreads();
    if (wid == 0) {
      int s = (lane < 16) ? wsum[lane] : 0;
#pragma unroll
      for (int off = 1; off < 16; off <<= 1) {
        int u = __shfl_up(s, off);
        if (lane >= off) s += u;
      }
      if (lane < 16) wsum[lane] = s;
    }
    __syncthreads();
    int add = carry + (wid ? wsum[wid - 1] : 0);
    if (base + t < NN) r[base + t + 1] = v + add;
    __syncthreads();
    if (t == 1023) carry = add + v;
    __syncthreads();
  }
}

// ---- counting-sort edges by target ---------------------------------------
__global__ void k_fill(const int* __restrict__ ei0, const int* __restrict__ ei1,
                       const float* __restrict__ ew0, const float* __restrict__ ew1,
                       const int* __restrict__ rp, int* __restrict__ cursor,
                       const float* __restrict__ dinv,
                       int* __restrict__ sr, float* __restrict__ snorm,
                       float* __restrict__ swt) {
  int b = blockIdx.y;
  int e = blockIdx.x * 256 + threadIdx.x;
  if (e >= EE) return;
  const int* ei = b ? ei1 : ei0;
  const float* ew = b ? ew1 : ew0;
  int r = ei[e], c = ei[EE + e];
  float w = ew[e];
  int pos = rp[b * (NN + 1) + c] + atomicAdd(cursor + b * NN + c, 1);
  size_t gp = (size_t)b * EE + pos;
  sr[gp] = r;
  snorm[gp] = dinv[b * NN + r] * w * dinv[b * NN + c];
  swt[gp] = w;
}

// ---- bf16 MFMA GEMM: C[M,N] = A[M,K] @ Bt[N,K]^T  (N%64==0, K%32==0) -----
// mode 0: write Cb row-major (+optional Cf fp32, +bias)
// mode 1: write interleaved hI[n][cc(128)][h(4)] for j<512, hg[n][j-512] else
__global__ __launch_bounds__(256) void k_mgemm(
    const unsigned short* __restrict__ A, int lda, long sA,
    const unsigned short* __restrict__ Bt, long sB,
    unsigned short* __restrict__ Cb, int ldc, long sC,
    float* __restrict__ Cf, long sCf,
    const float* __restrict__ bias0, const float* __restrict__ bias1,
    int M, int K, int mode,
    unsigned short* __restrict__ hI, unsigned short* __restrict__ hg) {
  int z = blockIdx.z;
  A += (size_t)z * sA;
  Bt += (size_t)z * sB;
  const float* bias = z ? bias1 : bias0;

  int w = threadIdx.x >> 6;
  int lane = threadIdx.x & 63;
  int lr = lane & 15, lg = lane >> 4;
  int n0 = blockIdx.x * 64 + w * 16;
  int m0 = blockIdx.y * 64;
  f32x4 acc[4] = {};
  for (int ks = 0; ks < K; ks += 32) {
    int kc = ks + lg * 8;
    bf16x8 bfr = *reinterpret_cast<const bf16x8*>(Bt + (size_t)(n0 + lr) * K + kc);
    bf16x8 a[4];
#pragma unroll
    for (int mt = 0; mt < 4; ++mt) {
      int row = m0 + mt * 16 + lr;
      bf16x8 v = {};
      if (row < M) v = *reinterpret_cast<const bf16x8*>(A + (size_t)row * lda + kc);
      a[mt] = v;
    }
#pragma unroll
    for (int mt = 0; mt < 4; ++mt)
      acc[mt] = __builtin_amdgcn_mfma_f32_16x16x32_bf16(a[mt], bfr, acc[mt], 0, 0, 0);
  }
  int col = n0 + lr;
  if (mode == 0) {
    Cb += (size_t)z * sC;
    if (Cf) Cf += (size_t)z * sCf;
    float bv = bias ? bias[col] : 0.f;
#pragma unroll
    for (int mt = 0; mt < 4; ++mt)
#pragma unroll
      for (int r = 0; r < 4; ++r) {
        int row = m0 + mt * 16 + lg * 4 + r;
        if (row < M) {
          float v = acc[mt][r] + bv;
          Cb[(size_t)row * ldc + col] = f2bf(v);
          if (Cf) Cf[(size_t)row * ldc + col] = v;
        }
      }
  } else {
    hI += (size_t)z * M * 512;
    hg += (size_t)z * M * 128;
    int ishead = col < 512;
    int h = col >> 7, cc = col & 127;
#pragma unroll
    for (int mt = 0; mt < 4; ++mt)
#pragma unroll
      for (int r = 0; r < 4; ++r) {
        int row = m0 + mt * 16 + lg * 4 + r;
        if (row < M) {
          unsigned short v = f2bf(acc[mt][r]);
          if (ishead) hI[(size_t)row * 512 + cc * 4 + h] = v;
          else hg[(size_t)row * 128 + (col - 512)] = v;
        }
      }
  }
}

// ---- per-node per-head attention pre-dots s,d (interleaved hI) -----------
__global__ __launch_bounds__(256) void k_sd(const unsigned short* __restrict__ hI,
                                            const float* __restrict__ as0,
                                            const float* __restrict__ as1,
                                            const float* __restrict__ ad0,
                                            const float* __restrict__ ad1,
                                            float* __restrict__ s, float* __restrict__ d) {
  int n = blockIdx.x;
  int b = n >= NN;
  const float* as = b ? as1 : as0;
  const float* ad = b ? ad1 : ad0;
  int t = threadIdx.x;
  int h = t >> 6, lane = t & 63;
  bf16x8 hv = *reinterpret_cast<const bf16x8*>(hI + (size_t)n * 512 + lane * 8);
  float e0 = bf2f((unsigned short)hv[h]);       // cc = 2*lane
  float e1 = bf2f((unsigned short)hv[4 + h]);   // cc = 2*lane+1
  int base = h * 128 + lane * 2;
  float ps = e0 * as[base] + e1 * as[base + 1];
  float pd = e0 * ad[base] + e1 * ad[base + 1];
  for (int off = 32; off > 0; off >>= 1) {
    ps += __shfl_down(ps, off);
    pd += __shfl_down(pd, off);
  }
  if (lane == 0) { s[n * 4 + h] = ps; d[n * 4 + h] = pd; }
}

// ---- fused GCN+GAT aggregate + combine + relu + bf16 store ---------------
__global__ __launch_bounds__(128) void k_agg(
    const int* __restrict__ rp, const int* __restrict__ sr,
    const float* __restrict__ snorm, const float* __restrict__ swt,
    const unsigned short* __restrict__ hI, const unsigned short* __restrict__ hg,
    const float* __restrict__ s, const float* __restrict__ d,
    const float* __restrict__ wd, const float* __restrict__ easum,
    const float* __restrict__ dinv,
    const float* __restrict__ gcnb0, const float* __restrict__ gcnb1,
    const float* __restrict__ gatb0, const float* __restrict__ gatb1,
    unsigned short* __restrict__ xcat, int colOff) {
  int n = blockIdx.x;
  int b = n >= NN;
  int nn = n - b * NN;
  int c = threadIdx.x;
  float eam = easum[b] * (1.f / (float)EE);
  float4 w4 = *reinterpret_cast<const float4*>(wd + b * 4);
  float4 sn = *reinterpret_cast<const float4*>(s + (size_t)n * 4);
  float4 dn = *reinterpret_cast<const float4*>(d + (size_t)n * 4);
  // self-loop (r = nn, edge attr = mean(ew), gcn w = 1)
  float p0 = lexp(sn.x + dn.x + eam * w4.x);
  float p1 = lexp(sn.y + dn.y + eam * w4.y);
  float p2 = lexp(sn.z + dn.z + eam * w4.z);
  float p3 = lexp(sn.w + dn.w + eam * w4.w);
  uint2 hv = *reinterpret_cast<const uint2*>(hI + (size_t)n * 512 + c * 4);
  float a0 = p0 * bf2f((unsigned short)(hv.x & 0xffff));
  float a1 = p1 * bf2f((unsigned short)(hv.x >> 16));
  float a2 = p2 * bf2f((unsigned short)(hv.y & 0xffff));
  float a3 = p3 * bf2f((unsigned short)(hv.y >> 16));
  float dv = dinv[b * NN + nn];
  float ag = dv * dv * bf2f(hg[(size_t)n * 128 + c]);
  float d0 = p0, d1 = p1, d2 = p2, d3 = p3;

  __shared__ int lr_[128];
  __shared__ float lnorm[128];
  __shared__ float lp[128][4];

  const int* rpb = rp + b * (NN + 1);
  int beg = rpb[nn], end = rpb[nn + 1];
  const unsigned short* hIb = hI + (size_t)b * NN * 512;
  const unsigned short* hgb = hg + (size_t)b * NN * 128;
  for (int ch = beg; ch < end; ch += 128) {
    int m = min(128, end - ch);
    __syncthreads();
    if (c < m) {
      size_t pos = (size_t)b * EE + ch + c;
      int r = sr[pos];
      float4 sv = *reinterpret_cast<const float4*>(s + ((size_t)b * NN + r) * 4);
      float w = swt[pos];
      lr_[c] = r;
      lnorm[c] = snorm[pos];
      lp[c][0] = lexp(sv.x + dn.x + w * w4.x);
      lp[c][1] = lexp(sv.y + dn.y + w * w4.y);
      lp[c][2] = lexp(sv.z + dn.z + w * w4.z);
      lp[c][3] = lexp(sv.w + dn.w + w * w4.w);
    }
    __syncthreads();
    for (int i = 0; i < m; ++i) {
      int r = lr_[i];
      uint2 rv = *reinterpret_cast<const uint2*>(hIb + (size_t)r * 512 + c * 4);
      float4 pv = *reinterpret_cast<const float4*>(lp[i]);
      float nr = lnorm[i];
      a0 += pv.x * bf2f((unsigned short)(rv.x & 0xffff));
      a1 += pv.y * bf2f((unsigned short)(rv.x >> 16));
      a2 += pv.z * bf2f((unsigned short)(rv.y & 0xffff));
      a3 += pv.w * bf2f((unsigned short)(rv.y >> 16));
      ag += nr * bf2f(hgb[(size_t)r * 128 + c]);
      d0 += pv.x; d1 += pv.y; d2 += pv.z; d3 += pv.w;
    }
  }
  float gat = 0.25f * (a0 / d0 + a1 / d1 + a2 / d2 + a3 / d3);
  float gcnb = (b ? gcnb1 : gcnb0)[c];
  float gatb = (b ? gatb1 : gatb0)[c];
  float l = ag + gcnb + gat + gatb;
  xcat[(size_t)n * 256 + colOff + c] = f2bf(fmaxf(0.5f * l, 0.f));
}

// ---- final MFMA: C[i,j] = sum_k drug[i,k]*dis[j,k] -----------------------
__global__ __launch_bounds__(256) void k_final(const unsigned short* __restrict__ Ab,
                                               const unsigned short* __restrict__ Bb,
                                               float* __restrict__ C) {
  int wave = threadIdx.x >> 6;
  int lane = threadIdx.x & 63;
  int wm = wave >> 1, wn = wave & 1;
  int m0 = blockIdx.y * 128 + wm * 64;
  int n0 = blockIdx.x * 128 + wn * 64;
  int lr = lane & 15;
  int lg = lane >> 4;
  f32x4 acc[4][4] = {};
#pragma unroll
  for (int ks = 0; ks < 4; ++ks) {
    int kcol = ks * 32 + lg * 8;
    bf16x8 a[4], b[4];
#pragma unroll
    for (int mt = 0; mt < 4; ++mt) {
      int row = m0 + mt * 16 + lr;
      bf16x8 v = {};
      if (row < NN) v = *reinterpret_cast<const bf16x8*>(Ab + (size_t)row * 128 + kcol);
      a[mt] = v;
    }
#pragma unroll
    for (int nt = 0; nt < 4; ++nt) {
      int rb = n0 + nt * 16 + lr;
      bf16x8 v = {};
      if (rb < NN) v = *reinterpret_cast<const bf16x8*>(Bb + (size_t)rb * 128 + kcol);
      b[nt] = v;
    }
#pragma unroll
    for (int mt = 0; mt < 4; ++mt)
#pragma unroll
      for (int nt = 0; nt < 4; ++nt)
        acc[mt][nt] = __builtin_amdgcn_mfma_f32_16x16x32_bf16(a[mt], b[nt], acc[mt][nt], 0, 0, 0);
  }
#pragma unroll
  for (int mt = 0; mt < 4; ++mt)
#pragma unroll
    for (int nt = 0; nt < 4; ++nt)
#pragma unroll
      for (int r = 0; r < 4; ++r) {
        int row = m0 + mt * 16 + lg * 4 + r;
        int col = n0 + nt * 16 + lr;
        if (row < NN && col < NN)
          __builtin_nontemporal_store(acc[mt][nt][r], C + (size_t)row * NN + col);
      }
}

// ==========================================================================
extern "C" void kernel_launch(void* const* d_in, const int* in_sizes, int n_in,
                              void* d_out, int out_size, void* d_ws, size_t ws_size,
                              hipStream_t stream) {
  char* wsp = (char*)d_ws;
  size_t off = 0;
  auto alloc = [&](size_t bytes) -> char* {
    char* ptr = wsp + off;
    off += (bytes + 255) & ~(size_t)255;
    return ptr;
  };
  // zero-region (one k_zero): deg, cnt, cursor, easum
  float* deg = (float*)alloc(2 * NN * 4);
  int* cnt = (int*)alloc(2 * NN * 4);
  int* cursor = (int*)alloc(2 * NN * 4);
  float* easum = (float*)alloc(256);
  size_t zero_bytes = (size_t)((char*)easum - (char*)deg) + 256;
  float* dinv = (float*)alloc(2 * NN * 4);
  int* rp = (int*)alloc(2 * (NN + 1) * 4);
  float* wd = (float*)alloc(256);
  int* sr = (int*)alloc((size_t)2 * EE * 4);
  float* snorm = (float*)alloc((size_t)2 * EE * 4);
  float* swt = (float*)alloc((size_t)2 * EE * 4);
  unsigned short* BcatT = (unsigned short*)alloc((size_t)327680 * 2);
  unsigned short* cWb = (unsigned short*)alloc((size_t)65536 * 2);
  unsigned short* xb = (unsigned short*)alloc((size_t)2 * NN * 128 * 2);
  unsigned short* hI = (unsigned short*)alloc((size_t)2 * NN * 512 * 2);
  unsigned short* hg = (unsigned short*)alloc((size_t)2 * NN * 128 * 2);
  float* sbuf = (float*)alloc((size_t)2 * NN * 4 * 4);
  float* dbuf = (float*)alloc((size_t)2 * NN * 4 * 4);
  unsigned short* xcat = (unsigned short*)alloc((size_t)2 * NN * 256 * 2);
  unsigned short* feab = (unsigned short*)alloc((size_t)2 * NN * 128 * 2);
  if (off > ws_size) return;  // fail loud (wrong output) rather than corrupt

  float* out = (float*)d_out;
  float* fea_dis = out + (size_t)36000000;          // b=0 slot; b=1 contiguous

  const float* x0 = (const float*)d_in[0];
  const float* x1 = (const float*)d_in[1];
  const int* ei0 = (const int*)d_in[2];
  const int* ei1 = (const int*)d_in[3];
  const float* ew0 = (const float*)d_in[4];
  const float* ew1 = (const float*)d_in[5];
  const float* g1W0 = (const float*)d_in[6];  const float* g1b0 = (const float*)d_in[7];
  const float* g2W0 = (const float*)d_in[8];  const float* g2b0 = (const float*)d_in[9];
  const float* gW0 = (const float*)d_in[10];  const float* gas0 = (const float*)d_in[11];
  const float* gad0 = (const float*)d_in[12]; const float* gWe0 = (const float*)d_in[13];
  const float* gae0 = (const float*)d_in[14]; const float* gb0 = (const float*)d_in[15];
  const float* cW0 = (const float*)d_in[16];  const float* cb0 = (const float*)d_in[17];
  const float* g1W1 = (const float*)d_in[18]; const float* g1b1 = (const float*)d_in[19];
  const float* g2W1 = (const float*)d_in[20]; const float* g2b1 = (const float*)d_in[21];
  const float* gW1 = (const float*)d_in[22];  const float* gas1 = (const float*)d_in[23];
  const float* gad1 = (const float*)d_in[24]; const float* gWe1 = (const float*)d_in[25];
  const float* gae1 = (const float*)d_in[26]; const float* gb1 = (const float*)d_in[27];
  const float* cW1 = (const float*)d_in[28];  const float* cb1 = (const float*)d_in[29];

  int zr16 = (int)(zero_bytes / 16);
  k_zero<<<(zr16 + 255) / 256, 256, 0, stream>>>((uint4*)deg, zr16);
  k_prep<<<7536, 256, 0, stream>>>(gW0, gW1, g1W0, g1W1, g2W0, g2W1, cW0, cW1,
                                   x0, x1, BcatT, cWb, xb);
  k_deg<<<dim3(563, 2), 256, 0, stream>>>(ei0, ei1, ew0, ew1, deg, cnt, easum);
  k_dinv<<<47, 256, 0, stream>>>(deg, dinv, gWe0, gWe1, gae0, gae1, wd);
  k_scan<<<2, 1024, 0, stream>>>(cnt, rp);
  k_fill<<<dim3(563, 2), 256, 0, stream>>>(ei0, ei1, ew0, ew1, rp, cursor, dinv,
                                           sr, snorm, swt);
  // layer 1: h = xb @ BcatT(L0)^T  -> interleaved hI/hg
  k_mgemm<<<dim3(10, 94, 2), 256, 0, stream>>>(
      xb, 128, (long)NN * 128, BcatT, 163840,
      nullptr, 0, 0, nullptr, 0, nullptr, nullptr, NN, 128, 1, hI, hg);
  k_sd<<<2 * NN, 256, 0, stream>>>(hI, gas0, gas1, gad0, gad1, sbuf, dbuf);
  k_agg<<<2 * NN, 128, 0, stream>>>(rp, sr, snorm, swt, hI, hg, sbuf, dbuf, wd,
                                    easum, dinv, g1b0, g1b1, gb0, gb1, xcat, 0);
  // layer 2
  k_mgemm<<<dim3(10, 94, 2), 256, 0, stream>>>(
      xcat, 256, (long)NN * 256, BcatT + 81920, 163840,
      nullptr, 0, 0, nullptr, 0, nullptr, nullptr, NN, 128, 1, hI, hg);
  k_sd<<<2 * NN, 256, 0, stream>>>(hI, gas0, gas1, gad0, gad1, sbuf, dbuf);
  k_agg<<<2 * NN, 128, 0, stream>>>(rp, sr, snorm, swt, hI, hg, sbuf, dbuf, wd,
                                    easum, dinv, g2b0, g2b1, gb0, gb1, xcat, 128);
  // fea = xcat @ cWb^T + cb  (fp32 to d_out, bf16 copy for final MFMA)
  k_mgemm<<<dim3(2, 94, 2), 256, 0, stream>>>(
      xcat, 256, (long)NN * 256, cWb, 32768,
      feab, 128, (long)NN * 128, fea_dis, (long)NN * 128, cb0, cb1, NN, 256, 0,
      nullptr, nullptr);
  // out = drug_fea @ dis_fea^T
  k_final<<<dim3(47, 47), 256, 0, stream>>>(feab + (size_t)NN * 128, feab, out);
}

// Round 4
// 282.277 us; speedup vs baseline: 1.0125x; 1.0125x over previous
//
#include <hip/hip_runtime.h>

#define NN 6000
#define EE 144000

typedef __attribute__((ext_vector_type(8))) short bf16x8;
typedef __attribute__((ext_vector_type(4))) float f32x4;

__device__ __forceinline__ unsigned short f2bf(float f) {
  unsigned int u = __float_as_uint(f);
  u += 0x7FFF + ((u >> 16) & 1);
  return (unsigned short)(u >> 16);
}
__device__ __forceinline__ float bf2f(unsigned short u) {
  return __uint_as_float(((unsigned int)u) << 16);
}
__device__ __forceinline__ float lexp(float v) {
  v = v > 0.f ? v : 0.2f * v;   // leaky_relu(0.2) then exp
  return __expf(v);
}

// ---- workspace zeroing (deg/cnt/cursor/easum) ----------------------------
__global__ void k_zero(uint4* __restrict__ p, int n16) {
  int i = blockIdx.x * 256 + threadIdx.x;
  if (i < n16) p[i] = uint4{0, 0, 0, 0};
}

// ---- prep: weight repacks + x->bf16 + was/wad dots + wd ------------------
// BcatT[(b*2+L)*704 + j][k]: j<512 gW, 512..639 WL, 640..647 was/wad, 648+ 0
__global__ void k_prep(const float* __restrict__ gW0, const float* __restrict__ gW1,
                       const float* __restrict__ g1W0, const float* __restrict__ g1W1,
                       const float* __restrict__ g2W0, const float* __restrict__ g2W1,
                       const float* __restrict__ cW0, const float* __restrict__ cW1,
                       const float* __restrict__ x0, const float* __restrict__ x1,
                       const float* __restrict__ gas0, const float* __restrict__ gas1,
                       const float* __restrict__ gad0, const float* __restrict__ gad1,
                       const float* __restrict__ We0, const float* __restrict__ We1,
                       const float* __restrict__ ae0, const float* __restrict__ ae1,
                       unsigned short* __restrict__ BcatT,
                       unsigned short* __restrict__ cWb,
                       unsigned short* __restrict__ xb,
                       float* __restrict__ wd) {
  int bid = blockIdx.x;
  int t = threadIdx.x;
  if (bid < 7664) {
    int idx = bid * 256 + t;
    if (idx < 360448) {
      int b = idx / 180224;
      int r = idx % 180224;
      int L = r / 90112;
      int r2 = r % 90112;
      int j = r2 / 128, k = r2 % 128;
      if (j >= 640 && j < 648) return;   // written by dot blocks
      const float* gW = b ? gW1 : gW0;
      const float* WL = L ? (b ? g2W1 : g2W0) : (b ? g1W1 : g1W0);
      float v = 0.f;
      if (j < 512) v = gW[k * 512 + j];
      else if (j < 640) v = WL[k * 128 + (j - 512)];
      BcatT[idx] = f2bf(v);
    } else if (idx < 425984) {
      int i2 = idx - 360448;
      int b = i2 >> 15;
      int ok = i2 & 32767;
      cWb[i2] = f2bf((b ? cW1 : cW0)[ok]);
    } else {
      int i3 = idx - 425984;   // < 1,536,000
      int b = i3 >= 768000;
      int local = i3 - b * 768000;
      xb[i3] = f2bf((b ? x1 : x0)[local]);
    }
  } else if (bid < 7792) {
    // was/wad: BcatT row 640+q, q<4: sum_c gW[k,h*128+c]*asrc[h,c]; q>=4: adst
    int db = bid - 7664;         // 0..127
    int b = db >> 6;
    int rem = db & 63;
    int q = rem >> 3;            // 0..7
    int kg = rem & 7;            // 0..7
    int kl = t >> 4, cc = t & 15;
    int k = kg * 16 + kl;
    const float* gW = b ? gW1 : gW0;
    int h = q & 3;
    const float* vec = (q < 4) ? (b ? gas1 : gas0) : (b ? gad1 : gad0);
    float p = 0.f;
#pragma unroll
    for (int c = 0; c < 8; ++c) {
      int cidx = h * 128 + cc * 8 + c;
      p += gW[k * 512 + cidx] * vec[cidx];
    }
#pragma unroll
    for (int off = 8; off > 0; off >>= 1) p += __shfl_down(p, off);
    if (cc == 0) {
      unsigned short v = f2bf(p);
      BcatT[(size_t)(b * 2 + 0) * 90112 + (640 + q) * 128 + k] = v;
      BcatT[(size_t)(b * 2 + 1) * 90112 + (640 + q) * 128 + k] = v;
    }
  } else {
    int b = bid - 7792;          // 0..1
    const float* We = b ? We1 : We0;
    const float* ae = b ? ae1 : ae0;
    int h = t >> 6, lane = t & 63;
    int f = h * 128 + lane * 2;
    float p = We[f] * ae[f] + We[f + 1] * ae[f + 1];
    for (int off = 32; off > 0; off >>= 1) p += __shfl_down(p, off);
    if (lane == 0) wd[b * 4 + h] = p;
  }
}

// ---- degrees / counts / mean(ew) -----------------------------------------
__global__ void k_deg(const int* __restrict__ ei0, const int* __restrict__ ei1,
                      const float* __restrict__ ew0, const float* __restrict__ ew1,
                      float* __restrict__ deg, int* __restrict__ cnt,
                      float* __restrict__ easum) {
  int b = blockIdx.y;
  int e = blockIdx.x * 256 + threadIdx.x;
  const int* ei = b ? ei1 : ei0;
  const float* ew = b ? ew1 : ew0;
  float w = 0.f;
  if (e < EE) {
    int c = ei[EE + e];
    w = ew[e];
    atomicAdd(deg + b * NN + c, w);
    atomicAdd(cnt + b * NN + c, 1);
  }
  __shared__ float red[256];
  red[threadIdx.x] = w;
  __syncthreads();
  for (int off = 128; off > 0; off >>= 1) {
    if (threadIdx.x < off) red[threadIdx.x] += red[threadIdx.x + off];
    __syncthreads();
  }
  if (threadIdx.x == 0) atomicAdd(easum + b, red[0]);
}

// ---- scan (blocks 0,1) + dinv (blocks 2..13) -----------------------------
__global__ __launch_bounds__(1024) void k_scan(const int* __restrict__ cnt,
                                               int* __restrict__ rp,
                                               const float* __restrict__ deg,
                                               float* __restrict__ dinv) {
  int bid = blockIdx.x;
  int t = threadIdx.x;
  if (bid >= 2) {
    int i = (bid - 2) * 1024 + t;
    if (i < 2 * NN) dinv[i] = rsqrtf(deg[i] + 1.0f);   // +1 = self-loop
    return;
  }
  int b = bid;
  const int* c = cnt + b * NN;
  int* r = rp + b * (NN + 1);
  __shared__ int wsum[16];
  __shared__ int carry;
  int lane = t & 63, wid = t >> 6;
  if (t == 0) { carry = 0; r[0] = 0; }
  __syncthreads();
  for (int base = 0; base < NN; base += 1024) {
    int v = (base + t < NN) ? c[base + t] : 0;
#pragma unroll
    for (int off = 1; off < 64; off <<= 1) {
      int u = __shfl_up(v, off);
      if (lane >= off) v += u;
    }
    if (lane == 63) wsum[wid] = v;
    __syncthreads();
    if (wid == 0) {
      int s = (lane < 16) ? wsum[lane] : 0;
#pragma unroll
      for (int off = 1; off < 16; off <<= 1) {
        int u = __shfl_up(s, off);
        if (lane >= off) s += u;
      }
      if (lane < 16) wsum[lane] = s;
    }
    __syncthreads();
    int add = carry + (wid ? wsum[wid - 1] : 0);
    if (base + t < NN) r[base + t + 1] = v + add;
    __syncthreads();
    if (t == 1023) carry = add + v;
    __syncthreads();
  }
}

// ---- counting-sort edges by target ---------------------------------------
__global__ void k_fill(const int* __restrict__ ei0, const int* __restrict__ ei1,
                       const float* __restrict__ ew0, const float* __restrict__ ew1,
                       const int* __restrict__ rp, int* __restrict__ cursor,
                       const float* __restrict__ dinv,
                       int* __restrict__ sr, float* __restrict__ snorm,
                       float* __restrict__ swt) {
  int b = blockIdx.y;
  int e = blockIdx.x * 256 + threadIdx.x;
  if (e >= EE) return;
  const int* ei = b ? ei1 : ei0;
  const float* ew = b ? ew1 : ew0;
  int r = ei[e], c = ei[EE + e];
  float w = ew[e];
  int pos = rp[b * (NN + 1) + c] + atomicAdd(cursor + b * NN + c, 1);
  size_t gp = (size_t)b * EE + pos;
  sr[gp] = r;
  snorm[gp] = dinv[b * NN + r] * w * dinv[b * NN + c];
  swt[gp] = w;
}

// ---- bf16 MFMA GEMM: C[M,N] = A[M,K] @ Bt[N,K]^T -------------------------
// mode 0: Cb row-major (+Cf fp32, +bias).  mode 1: scatter to hA/hB/hg/s/d.
__global__ __launch_bounds__(256) void k_mgemm(
    const unsigned short* __restrict__ A, int lda, long sA,
    const unsigned short* __restrict__ Bt, long sB,
    unsigned short* __restrict__ Cb, int ldc, long sC,
    float* __restrict__ Cf, long sCf,
    const float* __restrict__ bias0, const float* __restrict__ bias1,
    int M, int K, int mode,
    unsigned short* __restrict__ hA, unsigned short* __restrict__ hB,
    unsigned short* __restrict__ hg,
    float* __restrict__ sb, float* __restrict__ db2) {
  int z = blockIdx.z;
  A += (size_t)z * sA;
  Bt += (size_t)z * sB;
  const float* bias = z ? bias1 : bias0;

  int w = threadIdx.x >> 6;
  int lane = threadIdx.x & 63;
  int lr = lane & 15, lg = lane >> 4;
  int n0 = blockIdx.x * 64 + w * 16;
  int m0 = blockIdx.y * 64;
  f32x4 acc[4] = {};
  for (int ks = 0; ks < K; ks += 32) {
    int kc = ks + lg * 8;
    bf16x8 bfr = *reinterpret_cast<const bf16x8*>(Bt + (size_t)(n0 + lr) * K + kc);
    bf16x8 a[4];
#pragma unroll
    for (int mt = 0; mt < 4; ++mt) {
      int row = m0 + mt * 16 + lr;
      bf16x8 v = {};
      if (row < M) v = *reinterpret_cast<const bf16x8*>(A + (size_t)row * lda + kc);
      a[mt] = v;
    }
#pragma unroll
    for (int mt = 0; mt < 4; ++mt)
      acc[mt] = __builtin_amdgcn_mfma_f32_16x16x32_bf16(a[mt], bfr, acc[mt], 0, 0, 0);
  }
  int col = n0 + lr;
  if (mode == 0) {
    Cb += (size_t)z * sC;
    if (Cf) Cf += (size_t)z * sCf;
    float bv = bias ? bias[col] : 0.f;
#pragma unroll
    for (int mt = 0; mt < 4; ++mt)
#pragma unroll
      for (int r = 0; r < 4; ++r) {
        int row = m0 + mt * 16 + lg * 4 + r;
        if (row < M) {
          float v = acc[mt][r] + bv;
          Cb[(size_t)row * ldc + col] = f2bf(v);
          if (Cf) Cf[(size_t)row * ldc + col] = v;
        }
      }
  } else {
    unsigned short* hAz = hA + (size_t)z * NN * 256;
    unsigned short* hBz = hB + (size_t)z * NN * 256;
    unsigned short* hgz = hg + (size_t)z * NN * 128;
#pragma unroll
    for (int mt = 0; mt < 4; ++mt)
#pragma unroll
      for (int r = 0; r < 4; ++r) {
        int row = m0 + mt * 16 + lg * 4 + r;
        if (row >= M) continue;
        float v = acc[mt][r];
        if (col < 512) {
          int h = col >> 7, cc = col & 127;
          if (h < 2) hAz[(size_t)row * 256 + cc * 2 + h] = f2bf(v);
          else hBz[(size_t)row * 256 + cc * 2 + (h - 2)] = f2bf(v);
        } else if (col < 640) {
          hgz[(size_t)row * 128 + (col - 512)] = f2bf(v);
        } else if (col < 648) {
          int q = col - 640;
          if (q < 4) sb[((size_t)z * NN + row) * 4 + q] = v;
          else db2[((size_t)z * NN + row) * 4 + (q - 4)] = v;
        }
      }
  }
}

// ---- PASS A: heads 0,1 + GCN plane -> pacc (f32) -------------------------
__global__ __launch_bounds__(128) void k_aggA(
    const int* __restrict__ rp, const int* __restrict__ sr,
    const float* __restrict__ snorm, const float* __restrict__ swt,
    const unsigned short* __restrict__ hA, const unsigned short* __restrict__ hg,
    const float* __restrict__ s, const float* __restrict__ d,
    const float* __restrict__ wd, const float* __restrict__ easum,
    const float* __restrict__ dinv, float* __restrict__ pacc) {
  int n = blockIdx.x;
  int b = n >= NN;
  int nn = n - b * NN;
  int c = threadIdx.x;
  float eam = easum[b] * (1.f / (float)EE);
  float2 w2 = *reinterpret_cast<const float2*>(wd + b * 4);
  float2 sn = *reinterpret_cast<const float2*>(s + (size_t)n * 4);
  float2 dn = *reinterpret_cast<const float2*>(d + (size_t)n * 4);
  float p0 = lexp(sn.x + dn.x + eam * w2.x);
  float p1 = lexp(sn.y + dn.y + eam * w2.y);
  unsigned int hv = *reinterpret_cast<const unsigned int*>(hA + (size_t)n * 256 + c * 2);
  float a0 = p0 * bf2f((unsigned short)(hv & 0xffff));
  float a1 = p1 * bf2f((unsigned short)(hv >> 16));
  float dv = dinv[b * NN + nn];
  float ag = dv * dv * bf2f(hg[(size_t)n * 128 + c]);
  float d0 = p0, d1 = p1;

  __shared__ int lr_[128];
  __shared__ float lnorm[128];
  __shared__ float2 lp[128];

  const int* rpb = rp + b * (NN + 1);
  int beg = rpb[nn], end = rpb[nn + 1];
  const unsigned short* hAb = hA + (size_t)b * NN * 256;
  const unsigned short* hgb = hg + (size_t)b * NN * 128;
  for (int ch = beg; ch < end; ch += 128) {
    int m = min(128, end - ch);
    __syncthreads();
    if (c < m) {
      size_t pos = (size_t)b * EE + ch + c;
      int r = sr[pos];
      float2 sv = *reinterpret_cast<const float2*>(s + ((size_t)b * NN + r) * 4);
      float w = swt[pos];
      lr_[c] = r;
      lnorm[c] = snorm[pos];
      lp[c] = float2{lexp(sv.x + dn.x + w * w2.x), lexp(sv.y + dn.y + w * w2.y)};
    }
    __syncthreads();
    for (int i = 0; i < m; ++i) {
      int r = lr_[i];
      unsigned int rv = *reinterpret_cast<const unsigned int*>(hAb + (size_t)r * 256 + c * 2);
      float2 pv = lp[i];
      float nr = lnorm[i];
      a0 += pv.x * bf2f((unsigned short)(rv & 0xffff));
      a1 += pv.y * bf2f((unsigned short)(rv >> 16));
      ag += nr * bf2f(hgb[(size_t)r * 128 + c]);
      d0 += pv.x; d1 += pv.y;
    }
  }
  pacc[(size_t)n * 128 + c] = ag + 0.25f * (a0 / d0 + a1 / d1);
}

// ---- PASS B: heads 2,3 + combine + relu + bf16 store ---------------------
__global__ __launch_bounds__(128) void k_aggB(
    const int* __restrict__ rp, const int* __restrict__ sr,
    const float* __restrict__ swt,
    const unsigned short* __restrict__ hB,
    const float* __restrict__ s, const float* __restrict__ d,
    const float* __restrict__ wd, const float* __restrict__ easum,
    const float* __restrict__ pacc,
    const float* __restrict__ gcnb0, const float* __restrict__ gcnb1,
    const float* __restrict__ gatb0, const float* __restrict__ gatb1,
    unsigned short* __restrict__ xcat, int colOff) {
  int n = blockIdx.x;
  int b = n >= NN;
  int nn = n - b * NN;
  int c = threadIdx.x;
  float eam = easum[b] * (1.f / (float)EE);
  float2 w2 = *reinterpret_cast<const float2*>(wd + b * 4 + 2);
  float2 sn = *reinterpret_cast<const float2*>(s + (size_t)n * 4 + 2);
  float2 dn = *reinterpret_cast<const float2*>(d + (size_t)n * 4 + 2);
  float p2 = lexp(sn.x + dn.x + eam * w2.x);
  float p3 = lexp(sn.y + dn.y + eam * w2.y);
  unsigned int hv = *reinterpret_cast<const unsigned int*>(hB + (size_t)n * 256 + c * 2);
  float a2 = p2 * bf2f((unsigned short)(hv & 0xffff));
  float a3 = p3 * bf2f((unsigned short)(hv >> 16));
  float d2 = p2, d3 = p3;

  __shared__ int lr_[128];
  __shared__ float2 lp[128];

  const int* rpb = rp + b * (NN + 1);
  int beg = rpb[nn], end = rpb[nn + 1];
  const unsigned short* hBb = hB + (size_t)b * NN * 256;
  for (int ch = beg; ch < end; ch += 128) {
    int m = min(128, end - ch);
    __syncthreads();
    if (c < m) {
      size_t pos = (size_t)b * EE + ch + c;
      int r = sr[pos];
      float2 sv = *reinterpret_cast<const float2*>(s + ((size_t)b * NN + r) * 4 + 2);
      float w = swt[pos];
      lr_[c] = r;
      lp[c] = float2{lexp(sv.x + dn.x + w * w2.x), lexp(sv.y + dn.y + w * w2.y)};
    }
    __syncthreads();
    for (int i = 0; i < m; ++i) {
      int r = lr_[i];
      unsigned int rv = *reinterpret_cast<const unsigned int*>(hBb + (size_t)r * 256 + c * 2);
      float2 pv = lp[i];
      a2 += pv.x * bf2f((unsigned short)(rv & 0xffff));
      a3 += pv.y * bf2f((unsigned short)(rv >> 16));
      d2 += pv.x; d3 += pv.y;
    }
  }
  float gcnb = (b ? gcnb1 : gcnb0)[c];
  float gatb = (b ? gatb1 : gatb0)[c];
  float l = pacc[(size_t)n * 128 + c] + 0.25f * (a2 / d2 + a3 / d3) + gcnb + gatb;
  xcat[(size_t)n * 256 + colOff + c] = f2bf(fmaxf(0.5f * l, 0.f));
}

// ---- final MFMA: C[i,j] = sum_k drug[i,k]*dis[j,k] -----------------------
__global__ __launch_bounds__(256) void k_final(const unsigned short* __restrict__ Ab,
                                               const unsigned short* __restrict__ Bb,
                                               float* __restrict__ C) {
  int wave = threadIdx.x >> 6;
  int lane = threadIdx.x & 63;
  int wm = wave >> 1, wn = wave & 1;
  int m0 = blockIdx.y * 128 + wm * 64;
  int n0 = blockIdx.x * 128 + wn * 64;
  int lr = lane & 15;
  int lg = lane >> 4;
  f32x4 acc[4][4] = {};
#pragma unroll
  for (int ks = 0; ks < 4; ++ks) {
    int kcol = ks * 32 + lg * 8;
    bf16x8 a[4], b[4];
#pragma unroll
    for (int mt = 0; mt < 4; ++mt) {
      int row = m0 + mt * 16 + lr;
      bf16x8 v = {};
      if (row < NN) v = *reinterpret_cast<const bf16x8*>(Ab + (size_t)row * 128 + kcol);
      a[mt] = v;
    }
#pragma unroll
    for (int nt = 0; nt < 4; ++nt) {
      int rb = n0 + nt * 16 + lr;
      bf16x8 v = {};
      if (rb < NN) v = *reinterpret_cast<const bf16x8*>(Bb + (size_t)rb * 128 + kcol);
      b[nt] = v;
    }
#pragma unroll
    for (int mt = 0; mt < 4; ++mt)
#pragma unroll
      for (int nt = 0; nt < 4; ++nt)
        acc[mt][nt] = __builtin_amdgcn_mfma_f32_16x16x32_bf16(a[mt], b[nt], acc[mt][nt], 0, 0, 0);
  }
#pragma unroll
  for (int mt = 0; mt < 4; ++mt)
#pragma unroll
    for (int nt = 0; nt < 4; ++nt)
#pragma unroll
      for (int r = 0; r < 4; ++r) {
        int row = m0 + mt * 16 + lg * 4 + r;
        int col = n0 + nt * 16 + lr;
        if (row < NN && col < NN)
          __builtin_nontemporal_store(acc[mt][nt][r], C + (size_t)row * NN + col);
      }
}

// ==========================================================================
extern "C" void kernel_launch(void* const* d_in, const int* in_sizes, int n_in,
                              void* d_out, int out_size, void* d_ws, size_t ws_size,
                              hipStream_t stream) {
  char* wsp = (char*)d_ws;
  size_t off = 0;
  auto alloc = [&](size_t bytes) -> char* {
    char* ptr = wsp + off;
    off += (bytes + 255) & ~(size_t)255;
    return ptr;
  };
  // zero-region (one k_zero): deg, cnt, cursor, easum
  float* deg = (float*)alloc(2 * NN * 4);
  int* cnt = (int*)alloc(2 * NN * 4);
  int* cursor = (int*)alloc(2 * NN * 4);
  float* easum = (float*)alloc(256);
  size_t zero_bytes = (size_t)((char*)easum - (char*)deg) + 256;
  float* dinv = (float*)alloc(2 * NN * 4);
  int* rp = (int*)alloc(2 * (NN + 1) * 4);
  float* wd = (float*)alloc(256);
  int* sr = (int*)alloc((size_t)2 * EE * 4);
  float* snorm = (float*)alloc((size_t)2 * EE * 4);
  float* swt = (float*)alloc((size_t)2 * EE * 4);
  unsigned short* BcatT = (unsigned short*)alloc((size_t)360448 * 2);
  unsigned short* cWb = (unsigned short*)alloc((size_t)65536 * 2);
  unsigned short* xb = (unsigned short*)alloc((size_t)2 * NN * 128 * 2);
  unsigned short* hA = (unsigned short*)alloc((size_t)2 * NN * 256 * 2);
  unsigned short* hB = (unsigned short*)alloc((size_t)2 * NN * 256 * 2);
  unsigned short* hg = (unsigned short*)alloc((size_t)2 * NN * 128 * 2);
  float* sbuf = (float*)alloc((size_t)2 * NN * 4 * 4);
  float* dbuf = (float*)alloc((size_t)2 * NN * 4 * 4);
  float* pacc = (float*)alloc((size_t)2 * NN * 128 * 4);
  unsigned short* xcat = (unsigned short*)alloc((size_t)2 * NN * 256 * 2);
  unsigned short* feab = (unsigned short*)alloc((size_t)2 * NN * 128 * 2);
  if (off > ws_size) return;  // fail loud (wrong output) rather than corrupt

  float* out = (float*)d_out;
  float* fea_dis = out + (size_t)36000000;          // b=0 slot; b=1 contiguous

  const float* x0 = (const float*)d_in[0];
  const float* x1 = (const float*)d_in[1];
  const int* ei0 = (const int*)d_in[2];
  const int* ei1 = (const int*)d_in[3];
  const float* ew0 = (const float*)d_in[4];
  const float* ew1 = (const float*)d_in[5];
  const float* g1W0 = (const float*)d_in[6];  const float* g1b0 = (const float*)d_in[7];
  const float* g2W0 = (const float*)d_in[8];  const float* g2b0 = (const float*)d_in[9];
  const float* gW0 = (const float*)d_in[10];  const float* gas0 = (const float*)d_in[11];
  const float* gad0 = (const float*)d_in[12]; const float* gWe0 = (const float*)d_in[13];
  const float* gae0 = (const float*)d_in[14]; const float* gb0 = (const float*)d_in[15];
  const float* cW0 = (const float*)d_in[16];  const float* cb0 = (const float*)d_in[17];
  const float* g1W1 = (const float*)d_in[18]; const float* g1b1 = (const float*)d_in[19];
  const float* g2W1 = (const float*)d_in[20]; const float* g2b1 = (const float*)d_in[21];
  const float* gW1 = (const float*)d_in[22];  const float* gas1 = (const float*)d_in[23];
  const float* gad1 = (const float*)d_in[24]; const float* gWe1 = (const float*)d_in[25];
  const float* gae1 = (const float*)d_in[26]; const float* gb1 = (const float*)d_in[27];
  const float* cW1 = (const float*)d_in[28];  const float* cb1 = (const float*)d_in[29];

  int zr16 = (int)(zero_bytes / 16);
  k_zero<<<(zr16 + 255) / 256, 256, 0, stream>>>((uint4*)deg, zr16);
  k_prep<<<7794, 256, 0, stream>>>(gW0, gW1, g1W0, g1W1, g2W0, g2W1, cW0, cW1,
                                   x0, x1, gas0, gas1, gad0, gad1,
                                   gWe0, gWe1, gae0, gae1, BcatT, cWb, xb, wd);
  k_deg<<<dim3(563, 2), 256, 0, stream>>>(ei0, ei1, ew0, ew1, deg, cnt, easum);
  k_scan<<<14, 1024, 0, stream>>>(cnt, rp, deg, dinv);
  k_fill<<<dim3(563, 2), 256, 0, stream>>>(ei0, ei1, ew0, ew1, rp, cursor, dinv,
                                           sr, snorm, swt);
  // layer 1: h = xb @ BcatT(L0)^T  -> hA/hB/hg + s/d (appended cols)
  k_mgemm<<<dim3(11, 94, 2), 256, 0, stream>>>(
      xb, 128, (long)NN * 128, BcatT, 180224,
      nullptr, 0, 0, nullptr, 0, nullptr, nullptr, NN, 128, 1,
      hA, hB, hg, sbuf, dbuf);
  k_aggA<<<2 * NN, 128, 0, stream>>>(rp, sr, snorm, swt, hA, hg, sbuf, dbuf, wd,
                                     easum, dinv, pacc);
  k_aggB<<<2 * NN, 128, 0, stream>>>(rp, sr, swt, hB, sbuf, dbuf, wd, easum,
                                     pacc, g1b0, g1b1, gb0, gb1, xcat, 0);
  // layer 2 (A = xcat cols 0..127 = x1)
  k_mgemm<<<dim3(11, 94, 2), 256, 0, stream>>>(
      xcat, 256, (long)NN * 256, BcatT + 90112, 180224,
      nullptr, 0, 0, nullptr, 0, nullptr, nullptr, NN, 128, 1,
      hA, hB, hg, sbuf, dbuf);
  k_aggA<<<2 * NN, 128, 0, stream>>>(rp, sr, snorm, swt, hA, hg, sbuf, dbuf, wd,
                                     easum, dinv, pacc);
  k_aggB<<<2 * NN, 128, 0, stream>>>(rp, sr, swt, hB, sbuf, dbuf, wd, easum,
                                     pacc, g2b0, g2b1, gb0, gb1, xcat, 128);
  // fea = xcat @ cWb^T + cb  (fp32 to d_out, bf16 copy for final MFMA)
  k_mgemm<<<dim3(2, 94, 2), 256, 0, stream>>>(
      xcat, 256, (long)NN * 256, cWb, 32768,
      feab, 128, (long)NN * 128, fea_dis, (long)NN * 128, cb0, cb1, NN, 256, 0,
      nullptr, nullptr, nullptr, nullptr, nullptr);
  // out = drug_fea @ dis_fea^T
  k_final<<<dim3(47, 47), 256, 0, stream>>>(feab + (size_t)NN * 128, feab, out);
}